// Round 1
// baseline (564.570 us; speedup 1.0000x reference)
//
#include <hip/hip_runtime.h>

#define N_TOK 4096
#define DIM   1024
#define NE    16
#define NF    512
#define TOPK  4
#define CAP   4096

typedef _Float16 v8h __attribute__((ext_vector_type(8)));
typedef float    v4f __attribute__((ext_vector_type(4)));

// ---------------------------------------------------------------- router ----
// one wave per token: fp64 logits, top-4 (ties -> lowest index), renormalized
// weights, atomic append into per-expert buckets.
__global__ __launch_bounds__(64) void router_kernel(
    const float* __restrict__ x, const float* __restrict__ Wr,
    int* __restrict__ cnt, int* __restrict__ btok, float* __restrict__ bw)
{
    int t = blockIdx.x;
    int l = threadIdx.x;
    double z[NE];
#pragma unroll
    for (int e = 0; e < NE; e++) z[e] = 0.0;
    const float* xrow = x + (size_t)t * DIM;
#pragma unroll
    for (int i = 0; i < 16; i++) {
        int d = i * 64 + l;
        double xv = (double)xrow[d];
        const float4* wr = (const float4*)(Wr + d * NE);
        float4 w0 = wr[0], w1 = wr[1], w2 = wr[2], w3 = wr[3];
        z[0]  += xv * w0.x; z[1]  += xv * w0.y; z[2]  += xv * w0.z; z[3]  += xv * w0.w;
        z[4]  += xv * w1.x; z[5]  += xv * w1.y; z[6]  += xv * w1.z; z[7]  += xv * w1.w;
        z[8]  += xv * w2.x; z[9]  += xv * w2.y; z[10] += xv * w2.z; z[11] += xv * w2.w;
        z[12] += xv * w3.x; z[13] += xv * w3.y; z[14] += xv * w3.z; z[15] += xv * w3.w;
    }
#pragma unroll
    for (int e = 0; e < NE; e++) {
#pragma unroll
        for (int m = 1; m < 64; m <<= 1) z[e] += __shfl_xor(z[e], m, 64);
    }
    if (l == 0) {
        bool taken[NE];
#pragma unroll
        for (int e = 0; e < NE; e++) taken[e] = false;
        int idx[TOPK]; double sel[TOPK];
        for (int k = 0; k < TOPK; k++) {
            int bi = 0; double bv = -1.0e300;
            for (int e = 0; e < NE; e++)
                if (!taken[e] && z[e] > bv) { bv = z[e]; bi = e; }
            taken[bi] = true; idx[k] = bi; sel[k] = bv;
        }
        double m = sel[0];   // max logit (first pick)
        double ex[TOPK]; double s = 0.0;
        for (int k = 0; k < TOPK; k++) { ex[k] = exp(sel[k] - m); s += ex[k]; }
        for (int k = 0; k < TOPK; k++) {
            int e = idx[k];
            int pos = atomicAdd(&cnt[e], 1);
            btok[e * CAP + pos] = t;
            bw[e * CAP + pos]   = (float)(ex[k] / s);
        }
    }
}

__global__ void prefix_kernel(const int* __restrict__ cnt, int* __restrict__ offs) {
    if (threadIdx.x == 0) {
        int r = 0;
        for (int e = 0; e < NE; e++) { offs[e] = r; r += cnt[e]; }
    }
}

// ------------------------------------------------------------------ casts ----
__global__ __launch_bounds__(256) void cast_x_kernel(
    const float* __restrict__ x, unsigned short* __restrict__ xb)
{
    size_t base = ((size_t)blockIdx.x * 256 + threadIdx.x) * 8;
    float4 a = *(const float4*)(x + base);
    float4 b = *(const float4*)(x + base + 4);
    union { unsigned short u[8]; uint4 v; } p;
    p.u[0] = __builtin_bit_cast(unsigned short, (_Float16)a.x);
    p.u[1] = __builtin_bit_cast(unsigned short, (_Float16)a.y);
    p.u[2] = __builtin_bit_cast(unsigned short, (_Float16)a.z);
    p.u[3] = __builtin_bit_cast(unsigned short, (_Float16)a.w);
    p.u[4] = __builtin_bit_cast(unsigned short, (_Float16)b.x);
    p.u[5] = __builtin_bit_cast(unsigned short, (_Float16)b.y);
    p.u[6] = __builtin_bit_cast(unsigned short, (_Float16)b.z);
    p.u[7] = __builtin_bit_cast(unsigned short, (_Float16)b.w);
    *(uint4*)(xb + base) = p.v;
}

// src [E][R][C] f32 -> dst [E][C][R] f16   (B^T layout for MFMA B-frags)
__global__ __launch_bounds__(256) void transpose_cast_kernel(
    const float* __restrict__ src, unsigned short* __restrict__ dst, int R, int C)
{
    __shared__ float tile[64][65];
    int e = blockIdx.z;
    const float* s = src + (size_t)e * R * C;
    unsigned short* d = dst + (size_t)e * R * C;
    int c0 = blockIdx.x * 64, r0 = blockIdx.y * 64;
    int t = threadIdx.x;
    int tr = t >> 4, tc = (t & 15) * 4;
#pragma unroll
    for (int i = 0; i < 4; i++) {
        int row = i * 16 + tr;
        float4 v = *(const float4*)(s + (size_t)(r0 + row) * C + c0 + tc);
        tile[row][tc + 0] = v.x; tile[row][tc + 1] = v.y;
        tile[row][tc + 2] = v.z; tile[row][tc + 3] = v.w;
    }
    __syncthreads();
#pragma unroll
    for (int i = 0; i < 4; i++) {
        int nr = i * 16 + tr;
        union { unsigned short u[4]; uint2 v; } p;
#pragma unroll
        for (int j = 0; j < 4; j++)
            p.u[j] = __builtin_bit_cast(unsigned short, (_Float16)tile[tc + j][nr]);
        *(uint2*)(d + (size_t)(c0 + nr) * R + r0 + tc) = p.v;
    }
}

// --------------------------------------------------------- gate/up + silu ----
// block: 64 slots x 128 f-cols of one expert; h = silu(x@Wg) * (x@Wu)
__global__ __launch_bounds__(256) void ffn_gate_up_kernel(
    const unsigned short* __restrict__ xb,
    const unsigned short* __restrict__ WgT,   // [E][F][D] f16
    const unsigned short* __restrict__ WuT,   // [E][F][D] f16
    const int* __restrict__ cnt, const int* __restrict__ offs,
    const int* __restrict__ btok,
    unsigned short* __restrict__ h)           // [16384+64][F] f16 compact
{
    int e = blockIdx.z;
    int count = cnt[e];
    int mt = blockIdx.x;
    if (mt * 64 >= count) return;
    int fb = blockIdx.y;

    __shared__ __align__(16) unsigned short sX[64][40];   // +16B pad: 2-way max
    __shared__ __align__(16) unsigned short sG[128][40];
    __shared__ __align__(16) unsigned short sU[128][40];
    __shared__ int sTok[64];

    int tid = threadIdx.x;
    int lane = tid & 63;
    int wv = tid >> 6;

    if (tid < 64) {
        int pos = mt * 64 + tid;
        sTok[tid] = (pos < count) ? btok[e * CAP + pos] : 0;  // guard tail rows
    }
    __syncthreads();

    int sr = tid >> 2;            // staging row 0..63
    int sc = (tid & 3) * 8;       // element offset within 32-wide k-slab
    const unsigned short* xsrc = xb + (size_t)sTok[sr] * DIM + sc;
    const unsigned short* wg1 = WgT + ((size_t)e * NF + fb * 128 + sr) * DIM + sc;
    const unsigned short* wg2 = wg1 + (size_t)64 * DIM;
    const unsigned short* wu1 = WuT + ((size_t)e * NF + fb * 128 + sr) * DIM + sc;
    const unsigned short* wu2 = wu1 + (size_t)64 * DIM;

    v4f accG[4][2], accU[4][2];
    v4f zero = {0.f, 0.f, 0.f, 0.f};
#pragma unroll
    for (int mi = 0; mi < 4; mi++)
#pragma unroll
        for (int ni = 0; ni < 2; ni++) { accG[mi][ni] = zero; accU[mi][ni] = zero; }

    int row = lane & 15, q = lane >> 4;

    for (int k0 = 0; k0 < DIM; k0 += 32) {
        uint4 vx = *(const uint4*)(xsrc + k0);
        uint4 g1 = *(const uint4*)(wg1 + k0);
        uint4 g2 = *(const uint4*)(wg2 + k0);
        uint4 u1 = *(const uint4*)(wu1 + k0);
        uint4 u2 = *(const uint4*)(wu2 + k0);
        __syncthreads();
        *(uint4*)&sX[sr][sc]      = vx;
        *(uint4*)&sG[sr][sc]      = g1;
        *(uint4*)&sG[sr + 64][sc] = g2;
        *(uint4*)&sU[sr][sc]      = u1;
        *(uint4*)&sU[sr + 64][sc] = u2;
        __syncthreads();
        v8h a[4], bg[2], bu[2];
#pragma unroll
        for (int mi = 0; mi < 4; mi++)
            a[mi] = *(const v8h*)&sX[mi * 16 + row][q * 8];
#pragma unroll
        for (int ni = 0; ni < 2; ni++) {
            bg[ni] = *(const v8h*)&sG[wv * 32 + ni * 16 + row][q * 8];
            bu[ni] = *(const v8h*)&sU[wv * 32 + ni * 16 + row][q * 8];
        }
#pragma unroll
        for (int mi = 0; mi < 4; mi++)
#pragma unroll
            for (int ni = 0; ni < 2; ni++) {
                accG[mi][ni] = __builtin_amdgcn_mfma_f32_16x16x32_f16(a[mi], bg[ni], accG[mi][ni], 0, 0, 0);
                accU[mi][ni] = __builtin_amdgcn_mfma_f32_16x16x32_f16(a[mi], bu[ni], accU[mi][ni], 0, 0, 0);
            }
    }

    int obase = offs[e];
#pragma unroll
    for (int mi = 0; mi < 4; mi++)
#pragma unroll
        for (int ni = 0; ni < 2; ni++) {
            int colg = fb * 128 + wv * 32 + ni * 16 + row;   // C/D: col = lane&15
#pragma unroll
            for (int i = 0; i < 4; i++) {
                int rl = mi * 16 + q * 4 + i;                // C/D: row = quad*4+reg
                int pos = mt * 64 + rl;
                if (pos < count) {
                    float gv = accG[mi][ni][i];
                    float uv = accU[mi][ni][i];
                    float hv = gv * uv / (1.0f + __expf(-gv));   // silu(g)*u
                    h[(size_t)(obase + pos) * NF + colg] =
                        __builtin_bit_cast(unsigned short, (_Float16)hv);
                }
            }
        }
}

// ----------------------------------------------------------- down + combine --
__global__ __launch_bounds__(256) void ffn_down_kernel(
    const unsigned short* __restrict__ h,
    const unsigned short* __restrict__ WdT,   // [E][D][F] f16
    const int* __restrict__ cnt, const int* __restrict__ offs,
    const int* __restrict__ btok, const float* __restrict__ bw,
    float* __restrict__ out)
{
    int e = blockIdx.z;
    int count = cnt[e];
    int mt = blockIdx.x;
    if (mt * 64 >= count) return;
    int db = blockIdx.y;
    int obase = offs[e];

    __shared__ __align__(16) unsigned short sH[64][40];
    __shared__ __align__(16) unsigned short sW[128][40];
    __shared__ int sTok[64];
    __shared__ float sWt[64];

    int tid = threadIdx.x;
    int lane = tid & 63;
    int wv = tid >> 6;

    if (tid < 64) {
        int pos = mt * 64 + tid;
        sTok[tid] = (pos < count) ? btok[e * CAP + pos] : 0;
        sWt[tid]  = (pos < count) ? bw[e * CAP + pos] : 0.0f;
    }

    int sr = tid >> 2;
    int sc = (tid & 3) * 8;
    const unsigned short* hsrc = h + (size_t)(obase + mt * 64 + sr) * NF + sc; // 64-row pad covers tail
    const unsigned short* w1 = WdT + ((size_t)e * DIM + db * 128 + sr) * NF + sc;
    const unsigned short* w2 = w1 + (size_t)64 * NF;

    v4f acc[4][2];
    v4f zero = {0.f, 0.f, 0.f, 0.f};
#pragma unroll
    for (int mi = 0; mi < 4; mi++)
#pragma unroll
        for (int ni = 0; ni < 2; ni++) acc[mi][ni] = zero;

    int row = lane & 15, q = lane >> 4;

    for (int k0 = 0; k0 < NF; k0 += 32) {
        uint4 vh = *(const uint4*)(hsrc + k0);
        uint4 a1 = *(const uint4*)(w1 + k0);
        uint4 a2 = *(const uint4*)(w2 + k0);
        __syncthreads();
        *(uint4*)&sH[sr][sc]      = vh;
        *(uint4*)&sW[sr][sc]      = a1;
        *(uint4*)&sW[sr + 64][sc] = a2;
        __syncthreads();
        v8h a[4], b[2];
#pragma unroll
        for (int mi = 0; mi < 4; mi++)
            a[mi] = *(const v8h*)&sH[mi * 16 + row][q * 8];
#pragma unroll
        for (int ni = 0; ni < 2; ni++)
            b[ni] = *(const v8h*)&sW[wv * 32 + ni * 16 + row][q * 8];
#pragma unroll
        for (int mi = 0; mi < 4; mi++)
#pragma unroll
            for (int ni = 0; ni < 2; ni++)
                acc[mi][ni] = __builtin_amdgcn_mfma_f32_16x16x32_f16(a[mi], b[ni], acc[mi][ni], 0, 0, 0);
    }

#pragma unroll
    for (int mi = 0; mi < 4; mi++)
#pragma unroll
        for (int ni = 0; ni < 2; ni++) {
            int col = db * 128 + wv * 32 + ni * 16 + row;
#pragma unroll
            for (int i = 0; i < 4; i++) {
                int rl = mi * 16 + q * 4 + i;
                int pos = mt * 64 + rl;
                if (pos < count) {
                    float v = acc[mi][ni][i] * sWt[rl];
                    atomicAdd(out + (size_t)sTok[rl] * DIM + col, v);
                }
            }
        }
}

// ------------------------------------------------------------------- host ----
extern "C" void kernel_launch(void* const* d_in, const int* in_sizes, int n_in,
                              void* d_out, int out_size, void* d_ws, size_t ws_size,
                              hipStream_t stream)
{
    const float* x  = (const float*)d_in[0];
    const float* Wr = (const float*)d_in[1];
    const float* Wg = (const float*)d_in[2];
    const float* Wu = (const float*)d_in[3];
    const float* Wd = (const float*)d_in[4];
    float* out = (float*)d_out;
    char* ws = (char*)d_ws;

    size_t off = 0;
    int* cnt  = (int*)(ws + off); off += 256;
    int* offs = (int*)(ws + off); off += 256;
    int* btok = (int*)(ws + off);   off += (size_t)NE * CAP * 4;
    float* bw = (float*)(ws + off); off += (size_t)NE * CAP * 4;
    unsigned short* xb  = (unsigned short*)(ws + off); off += (size_t)N_TOK * DIM * 2;
    unsigned short* WgT = (unsigned short*)(ws + off); off += (size_t)NE * DIM * NF * 2;
    unsigned short* WuT = (unsigned short*)(ws + off); off += (size_t)NE * DIM * NF * 2;
    unsigned short* WdT = (unsigned short*)(ws + off); off += (size_t)NE * DIM * NF * 2;
    unsigned short* hbuf = (unsigned short*)(ws + off);
    off += (size_t)(N_TOK * TOPK + 64) * NF * 2;   // ~76 MB total

    hipMemsetAsync(cnt, 0, 64, stream);
    hipMemsetAsync(out, 0, (size_t)N_TOK * DIM * sizeof(float), stream);

    router_kernel<<<N_TOK, 64, 0, stream>>>(x, Wr, cnt, btok, bw);
    prefix_kernel<<<1, 64, 0, stream>>>(cnt, offs);
    cast_x_kernel<<<(N_TOK * DIM) / (256 * 8), 256, 0, stream>>>(x, xb);
    transpose_cast_kernel<<<dim3(NF / 64, DIM / 64, NE), 256, 0, stream>>>(Wg, WgT, DIM, NF);
    transpose_cast_kernel<<<dim3(NF / 64, DIM / 64, NE), 256, 0, stream>>>(Wu, WuT, DIM, NF);
    transpose_cast_kernel<<<dim3(DIM / 64, NF / 64, NE), 256, 0, stream>>>(Wd, WdT, NF, DIM);
    ffn_gate_up_kernel<<<dim3(64, 4, NE), 256, 0, stream>>>(xb, WgT, WuT, cnt, offs, btok, hbuf);
    ffn_down_kernel<<<dim3(64, 8, NE), 256, 0, stream>>>(hbuf, WdT, cnt, offs, btok, bw, out);
}

// Round 2
// 451.383 us; speedup vs baseline: 1.2508x; 1.2508x over previous
//
#include <hip/hip_runtime.h>

#define N_TOK 4096
#define DIM   1024
#define NE    16
#define NF    512
#define TOPK  4
#define CAP   4096
#define NPAIR (N_TOK * TOPK)

typedef _Float16 v8h __attribute__((ext_vector_type(8)));
typedef float    v4f __attribute__((ext_vector_type(4)));

// ---------------------------------------------------------------- router ----
// one wave per token: fp64 logits, top-4 (ties -> lowest index), renormalized
// weights written per-token (NO global atomics — R1's 211us was atomic
// serialization on 16 counters in one cacheline).
__global__ __launch_bounds__(64) void router_kernel(
    const float* __restrict__ x, const float* __restrict__ Wr,
    int* __restrict__ tokIdx, float* __restrict__ tokW)
{
    int t = blockIdx.x;
    int l = threadIdx.x;
    double z[NE];
#pragma unroll
    for (int e = 0; e < NE; e++) z[e] = 0.0;
    const float* xrow = x + (size_t)t * DIM;
#pragma unroll
    for (int i = 0; i < 16; i++) {
        int d = i * 64 + l;
        double xv = (double)xrow[d];
        const float4* wr = (const float4*)(Wr + d * NE);
        float4 w0 = wr[0], w1 = wr[1], w2 = wr[2], w3 = wr[3];
        z[0]  += xv * w0.x; z[1]  += xv * w0.y; z[2]  += xv * w0.z; z[3]  += xv * w0.w;
        z[4]  += xv * w1.x; z[5]  += xv * w1.y; z[6]  += xv * w1.z; z[7]  += xv * w1.w;
        z[8]  += xv * w2.x; z[9]  += xv * w2.y; z[10] += xv * w2.z; z[11] += xv * w2.w;
        z[12] += xv * w3.x; z[13] += xv * w3.y; z[14] += xv * w3.z; z[15] += xv * w3.w;
    }
#pragma unroll
    for (int e = 0; e < NE; e++) {
#pragma unroll
        for (int m = 1; m < 64; m <<= 1) z[e] += __shfl_xor(z[e], m, 64);
    }
    if (l == 0) {
        bool taken[NE];
#pragma unroll
        for (int e = 0; e < NE; e++) taken[e] = false;
        int idx[TOPK]; double sel[TOPK];
        for (int k = 0; k < TOPK; k++) {
            int bi = 0; double bv = -1.0e300;
            for (int e = 0; e < NE; e++)
                if (!taken[e] && z[e] > bv) { bv = z[e]; bi = e; }
            taken[bi] = true; idx[k] = bi; sel[k] = bv;
        }
        double m = sel[0];   // max logit (first pick)
        double ex[TOPK]; double s = 0.0;
        for (int k = 0; k < TOPK; k++) { ex[k] = exp(sel[k] - m); s += ex[k]; }
        for (int k = 0; k < TOPK; k++) {
            tokIdx[t * TOPK + k] = idx[k];
            tokW[t * TOPK + k]   = (float)(ex[k] / s);
        }
    }
}

// ------------------------------------------------------------------ binning --
// single workgroup, 16 waves: wave e packs expert e's bucket via ballot/rank.
// Zero global atomics; deterministic. Also emits cnt + exclusive-prefix offs.
__global__ __launch_bounds__(1024) void bin_kernel(
    const int* __restrict__ tokIdx, const float* __restrict__ tokW,
    int* __restrict__ cnt, int* __restrict__ offs,
    int* __restrict__ btok, float* __restrict__ bwt)
{
    int wv = threadIdx.x >> 6;    // expert handled by this wave
    int lane = threadIdx.x & 63;
    __shared__ int scnt[NE];

    // pass 1: per-expert totals
    int c = 0;
    for (int i0 = lane * 4; i0 < NPAIR; i0 += 256) {
        int4 v = *(const int4*)(tokIdx + i0);
        c += (v.x == wv) + (v.y == wv) + (v.z == wv) + (v.w == wv);
    }
#pragma unroll
    for (int m = 1; m < 64; m <<= 1) c += __shfl_xor(c, m, 64);
    if (lane == 0) scnt[wv] = c;
    __syncthreads();
    if (threadIdx.x == 0) {
        int r = 0;
        for (int e = 0; e < NE; e++) {
            cnt[e] = scnt[e];
            offs[e] = r;
            r += scnt[e];
        }
    }

    // pass 2: scatter (order within bucket is arbitrary but deterministic)
    int pos = 0;
    for (int i0b = 0; i0b < NPAIR; i0b += 256) {
        int i0 = i0b + lane * 4;
        int4 v = *(const int4*)(tokIdx + i0);
        int ev[4] = {v.x, v.y, v.z, v.w};
#pragma unroll
        for (int j = 0; j < 4; j++) {
            bool m = (ev[j] == wv);
            unsigned long long bal = __ballot(m);
            if (m) {
                int r = __popcll(bal & ((1ULL << lane) - 1ULL));
                int p = i0 + j;                 // pair index = token*TOPK + k
                btok[wv * CAP + pos + r] = p >> 2;
                bwt [wv * CAP + pos + r] = tokW[p];
            }
            pos += __popcll(bal);
        }
    }
}

// ------------------------------------------------------------------ casts ----
__global__ __launch_bounds__(256) void cast_x_kernel(
    const float* __restrict__ x, unsigned short* __restrict__ xb)
{
    size_t base = ((size_t)blockIdx.x * 256 + threadIdx.x) * 8;
    float4 a = *(const float4*)(x + base);
    float4 b = *(const float4*)(x + base + 4);
    union { unsigned short u[8]; uint4 v; } p;
    p.u[0] = __builtin_bit_cast(unsigned short, (_Float16)a.x);
    p.u[1] = __builtin_bit_cast(unsigned short, (_Float16)a.y);
    p.u[2] = __builtin_bit_cast(unsigned short, (_Float16)a.z);
    p.u[3] = __builtin_bit_cast(unsigned short, (_Float16)a.w);
    p.u[4] = __builtin_bit_cast(unsigned short, (_Float16)b.x);
    p.u[5] = __builtin_bit_cast(unsigned short, (_Float16)b.y);
    p.u[6] = __builtin_bit_cast(unsigned short, (_Float16)b.z);
    p.u[7] = __builtin_bit_cast(unsigned short, (_Float16)b.w);
    *(uint4*)(xb + base) = p.v;
}

// src [E][R][C] f32 -> dst [E][C][R] f16   (B^T layout for MFMA B-frags)
__global__ __launch_bounds__(256) void transpose_cast_kernel(
    const float* __restrict__ src, unsigned short* __restrict__ dst, int R, int C)
{
    __shared__ float tile[64][65];
    int e = blockIdx.z;
    const float* s = src + (size_t)e * R * C;
    unsigned short* d = dst + (size_t)e * R * C;
    int c0 = blockIdx.x * 64, r0 = blockIdx.y * 64;
    int t = threadIdx.x;
    int tr = t >> 4, tc = (t & 15) * 4;
#pragma unroll
    for (int i = 0; i < 4; i++) {
        int row = i * 16 + tr;
        float4 v = *(const float4*)(s + (size_t)(r0 + row) * C + c0 + tc);
        tile[row][tc + 0] = v.x; tile[row][tc + 1] = v.y;
        tile[row][tc + 2] = v.z; tile[row][tc + 3] = v.w;
    }
    __syncthreads();
#pragma unroll
    for (int i = 0; i < 4; i++) {
        int nr = i * 16 + tr;
        union { unsigned short u[4]; uint2 v; } p;
#pragma unroll
        for (int j = 0; j < 4; j++)
            p.u[j] = __builtin_bit_cast(unsigned short, (_Float16)tile[tc + j][nr]);
        *(uint2*)(d + (size_t)(c0 + nr) * R + r0 + tc) = p.v;
    }
}

// --------------------------------------------------------- gate/up + silu ----
// block: 64 slots x 128 f-cols of one expert; h = silu(x@Wg) * (x@Wu)
__global__ __launch_bounds__(256) void ffn_gate_up_kernel(
    const unsigned short* __restrict__ xb,
    const unsigned short* __restrict__ WgT,   // [E][F][D] f16
    const unsigned short* __restrict__ WuT,   // [E][F][D] f16
    const int* __restrict__ cnt, const int* __restrict__ offs,
    const int* __restrict__ btok,
    unsigned short* __restrict__ h)           // [16384+64][F] f16 compact
{
    int e = blockIdx.z;
    int count = cnt[e];
    int mt = blockIdx.x;
    if (mt * 64 >= count) return;
    int fb = blockIdx.y;

    __shared__ __align__(16) unsigned short sX[64][40];   // +16B pad: 2-way max
    __shared__ __align__(16) unsigned short sG[128][40];
    __shared__ __align__(16) unsigned short sU[128][40];
    __shared__ int sTok[64];

    int tid = threadIdx.x;
    int lane = tid & 63;
    int wv = tid >> 6;

    if (tid < 64) {
        int pos = mt * 64 + tid;
        sTok[tid] = (pos < count) ? btok[e * CAP + pos] : 0;  // guard tail rows
    }
    __syncthreads();

    int sr = tid >> 2;            // staging row 0..63
    int sc = (tid & 3) * 8;       // element offset within 32-wide k-slab
    const unsigned short* xsrc = xb + (size_t)sTok[sr] * DIM + sc;
    const unsigned short* wg1 = WgT + ((size_t)e * NF + fb * 128 + sr) * DIM + sc;
    const unsigned short* wg2 = wg1 + (size_t)64 * DIM;
    const unsigned short* wu1 = WuT + ((size_t)e * NF + fb * 128 + sr) * DIM + sc;
    const unsigned short* wu2 = wu1 + (size_t)64 * DIM;

    v4f accG[4][2], accU[4][2];
    v4f zero = {0.f, 0.f, 0.f, 0.f};
#pragma unroll
    for (int mi = 0; mi < 4; mi++)
#pragma unroll
        for (int ni = 0; ni < 2; ni++) { accG[mi][ni] = zero; accU[mi][ni] = zero; }

    int row = lane & 15, q = lane >> 4;

    for (int k0 = 0; k0 < DIM; k0 += 32) {
        uint4 vx = *(const uint4*)(xsrc + k0);
        uint4 g1 = *(const uint4*)(wg1 + k0);
        uint4 g2 = *(const uint4*)(wg2 + k0);
        uint4 u1 = *(const uint4*)(wu1 + k0);
        uint4 u2 = *(const uint4*)(wu2 + k0);
        __syncthreads();
        *(uint4*)&sX[sr][sc]      = vx;
        *(uint4*)&sG[sr][sc]      = g1;
        *(uint4*)&sG[sr + 64][sc] = g2;
        *(uint4*)&sU[sr][sc]      = u1;
        *(uint4*)&sU[sr + 64][sc] = u2;
        __syncthreads();
        v8h a[4], bg[2], bu[2];
#pragma unroll
        for (int mi = 0; mi < 4; mi++)
            a[mi] = *(const v8h*)&sX[mi * 16 + row][q * 8];
#pragma unroll
        for (int ni = 0; ni < 2; ni++) {
            bg[ni] = *(const v8h*)&sG[wv * 32 + ni * 16 + row][q * 8];
            bu[ni] = *(const v8h*)&sU[wv * 32 + ni * 16 + row][q * 8];
        }
#pragma unroll
        for (int mi = 0; mi < 4; mi++)
#pragma unroll
            for (int ni = 0; ni < 2; ni++) {
                accG[mi][ni] = __builtin_amdgcn_mfma_f32_16x16x32_f16(a[mi], bg[ni], accG[mi][ni], 0, 0, 0);
                accU[mi][ni] = __builtin_amdgcn_mfma_f32_16x16x32_f16(a[mi], bu[ni], accU[mi][ni], 0, 0, 0);
            }
    }

    int obase = offs[e];
#pragma unroll
    for (int mi = 0; mi < 4; mi++)
#pragma unroll
        for (int ni = 0; ni < 2; ni++) {
            int colg = fb * 128 + wv * 32 + ni * 16 + row;   // C/D: col = lane&15
#pragma unroll
            for (int i = 0; i < 4; i++) {
                int rl = mi * 16 + q * 4 + i;                // C/D: row = quad*4+reg
                int pos = mt * 64 + rl;
                if (pos < count) {
                    float gv = accG[mi][ni][i];
                    float uv = accU[mi][ni][i];
                    float hv = gv * uv / (1.0f + __expf(-gv));   // silu(g)*u
                    h[(size_t)(obase + pos) * NF + colg] =
                        __builtin_bit_cast(unsigned short, (_Float16)hv);
                }
            }
        }
}

// ----------------------------------------------------------- down + combine --
__global__ __launch_bounds__(256) void ffn_down_kernel(
    const unsigned short* __restrict__ h,
    const unsigned short* __restrict__ WdT,   // [E][D][F] f16
    const int* __restrict__ cnt, const int* __restrict__ offs,
    const int* __restrict__ btok, const float* __restrict__ bw,
    float* __restrict__ out)
{
    int e = blockIdx.z;
    int count = cnt[e];
    int mt = blockIdx.x;
    if (mt * 64 >= count) return;
    int db = blockIdx.y;
    int obase = offs[e];

    __shared__ __align__(16) unsigned short sH[64][40];
    __shared__ __align__(16) unsigned short sW[128][40];
    __shared__ int sTok[64];
    __shared__ float sWt[64];

    int tid = threadIdx.x;
    int lane = tid & 63;
    int wv = tid >> 6;

    if (tid < 64) {
        int pos = mt * 64 + tid;
        sTok[tid] = (pos < count) ? btok[e * CAP + pos] : 0;
        sWt[tid]  = (pos < count) ? bw[e * CAP + pos] : 0.0f;
    }

    int sr = tid >> 2;
    int sc = (tid & 3) * 8;
    const unsigned short* hsrc = h + (size_t)(obase + mt * 64 + sr) * NF + sc; // 64-row pad covers tail
    const unsigned short* w1 = WdT + ((size_t)e * DIM + db * 128 + sr) * NF + sc;
    const unsigned short* w2 = w1 + (size_t)64 * NF;

    v4f acc[4][2];
    v4f zero = {0.f, 0.f, 0.f, 0.f};
#pragma unroll
    for (int mi = 0; mi < 4; mi++)
#pragma unroll
        for (int ni = 0; ni < 2; ni++) acc[mi][ni] = zero;

    int row = lane & 15, q = lane >> 4;

    for (int k0 = 0; k0 < NF; k0 += 32) {
        uint4 vh = *(const uint4*)(hsrc + k0);
        uint4 a1 = *(const uint4*)(w1 + k0);
        uint4 a2 = *(const uint4*)(w2 + k0);
        __syncthreads();
        *(uint4*)&sH[sr][sc]      = vh;
        *(uint4*)&sW[sr][sc]      = a1;
        *(uint4*)&sW[sr + 64][sc] = a2;
        __syncthreads();
        v8h a[4], b[2];
#pragma unroll
        for (int mi = 0; mi < 4; mi++)
            a[mi] = *(const v8h*)&sH[mi * 16 + row][q * 8];
#pragma unroll
        for (int ni = 0; ni < 2; ni++)
            b[ni] = *(const v8h*)&sW[wv * 32 + ni * 16 + row][q * 8];
#pragma unroll
        for (int mi = 0; mi < 4; mi++)
#pragma unroll
            for (int ni = 0; ni < 2; ni++)
                acc[mi][ni] = __builtin_amdgcn_mfma_f32_16x16x32_f16(a[mi], b[ni], acc[mi][ni], 0, 0, 0);
    }

#pragma unroll
    for (int mi = 0; mi < 4; mi++)
#pragma unroll
        for (int ni = 0; ni < 2; ni++) {
            int col = db * 128 + wv * 32 + ni * 16 + row;
#pragma unroll
            for (int i = 0; i < 4; i++) {
                int rl = mi * 16 + q * 4 + i;
                int pos = mt * 64 + rl;
                if (pos < count) {
                    float v = acc[mi][ni][i] * sWt[rl];
                    atomicAdd(out + (size_t)sTok[rl] * DIM + col, v);
                }
            }
        }
}

// ------------------------------------------------------------------- host ----
extern "C" void kernel_launch(void* const* d_in, const int* in_sizes, int n_in,
                              void* d_out, int out_size, void* d_ws, size_t ws_size,
                              hipStream_t stream)
{
    const float* x  = (const float*)d_in[0];
    const float* Wr = (const float*)d_in[1];
    const float* Wg = (const float*)d_in[2];
    const float* Wu = (const float*)d_in[3];
    const float* Wd = (const float*)d_in[4];
    float* out = (float*)d_out;
    char* ws = (char*)d_ws;

    size_t off = 0;
    int* cnt  = (int*)(ws + off); off += 256;
    int* offs = (int*)(ws + off); off += 256;
    int* tokIdx = (int*)(ws + off);   off += (size_t)NPAIR * 4;
    float* tokW = (float*)(ws + off); off += (size_t)NPAIR * 4;
    int* btok = (int*)(ws + off);   off += (size_t)NE * CAP * 4;
    float* bw = (float*)(ws + off); off += (size_t)NE * CAP * 4;
    unsigned short* xb  = (unsigned short*)(ws + off); off += (size_t)N_TOK * DIM * 2;
    unsigned short* WgT = (unsigned short*)(ws + off); off += (size_t)NE * DIM * NF * 2;
    unsigned short* WuT = (unsigned short*)(ws + off); off += (size_t)NE * DIM * NF * 2;
    unsigned short* WdT = (unsigned short*)(ws + off); off += (size_t)NE * DIM * NF * 2;
    unsigned short* hbuf = (unsigned short*)(ws + off);
    off += (size_t)(N_TOK * TOPK + 64) * NF * 2;   // ~76 MB total

    hipMemsetAsync(out, 0, (size_t)N_TOK * DIM * sizeof(float), stream);

    router_kernel<<<N_TOK, 64, 0, stream>>>(x, Wr, tokIdx, tokW);
    bin_kernel<<<1, 1024, 0, stream>>>(tokIdx, tokW, cnt, offs, btok, bw);
    cast_x_kernel<<<(N_TOK * DIM) / (256 * 8), 256, 0, stream>>>(x, xb);
    transpose_cast_kernel<<<dim3(NF / 64, DIM / 64, NE), 256, 0, stream>>>(Wg, WgT, DIM, NF);
    transpose_cast_kernel<<<dim3(NF / 64, DIM / 64, NE), 256, 0, stream>>>(Wu, WuT, DIM, NF);
    transpose_cast_kernel<<<dim3(DIM / 64, NF / 64, NE), 256, 0, stream>>>(Wd, WdT, NF, DIM);
    ffn_gate_up_kernel<<<dim3(64, 4, NE), 256, 0, stream>>>(xb, WgT, WuT, cnt, offs, btok, hbuf);
    ffn_down_kernel<<<dim3(64, 8, NE), 256, 0, stream>>>(hbuf, WdT, cnt, offs, btok, bw, out);
}